// Round 7
// baseline (95.174 us; speedup 1.0000x reference)
//
#include <hip/hip_runtime.h>

typedef float f32x4 __attribute__((ext_vector_type(4)));
typedef __bf16 bf16x8 __attribute__((ext_vector_type(8)));
typedef unsigned short u16x8 __attribute__((ext_vector_type(8)));

#define NB 4
#define NH 16
#define TT 4096
#define DD 64
#define LOG2E 1.4426950408889634f
#define QSCALE (LOG2E * 0.125f)   // (1/sqrt(64)) * log2(e)
#define THR 8.0f                  // defer-rescale threshold (log2 domain)

__device__ __forceinline__ unsigned cvt_pk_bf16(float a, float b) {
  unsigned r;
  asm("v_cvt_pk_bf16_f32 %0, %1, %2" : "=v"(r) : "v"(a), "v"(b));
  return r;   // lo16 = bf16(a), hi16 = bf16(b)  (RNE)
}
__device__ __forceinline__ float exp2_hw(float x) {
  float r;
  asm("v_exp_f32 %0, %1" : "=v"(r) : "v"(x));
  return r;
}
__device__ __forceinline__ float max3f(float a, float b, float c) {
  float r;
  asm("v_max3_f32 %0, %1, %2, %3" : "=v"(r) : "v"(a), "v"(b), "v"(c));
  return r;
}

// V LDS swizzle (ushort units), tile [256][64].
// Read as scalar u16 with 4 distinct keys (differing in bits 2..3) per instr.
__device__ __forceinline__ int vswz(int key, int d) {
  return ((key << 6) + d) ^ (((key >> 2) & 3) << 4);
}

__global__ __launch_bounds__(256, 4) void swa_fwd(
    const float* __restrict__ Qg, const float* __restrict__ Kg,
    const float* __restrict__ Vg, const float* __restrict__ Mg,
    float* __restrict__ Og) {
  // 32 KiB static LDS (V only) -> 5 blocks/CU by LDS; regs target 4 waves/SIMD.
  __shared__ unsigned short vvs[256 * 64];

  // XCD-bijective swizzle: 2048 blocks, 8 XCDs, contiguous work per XCD.
  const int bid = blockIdx.x;
  const int flat = (bid & 7) * 256 + (bid >> 3);
  const int i = flat & 31;        // q-block
  const int bh = flat >> 5;       // b*NH + h
  const int b = bh >> 4;

  const int t = threadIdx.x;
  const int lane = t & 63;
  const int wid = t >> 6;
  const int lr = lane & 15;
  const int g = lane >> 4;

  const size_t base = (size_t)bh * (TT * DD);
  const float* Qb = Qg + base;
  const float* Kb = Kg + base;
  const float* Vb = Vg + base;
  const float* Mb = Mg + (size_t)b * TT;
  const int j0 = i * 128 - 128;           // window start (may be -128 for i==0)
  const int qrow0 = i * 128 + wid * 32;   // this wave's 32 rows

  // ---- early Q loads ----
  f32x4 qraw[2][2][2];
#pragma unroll
  for (int nt = 0; nt < 2; ++nt)
#pragma unroll
    for (int s = 0; s < 2; ++s) {
      const float* qp = Qb + (size_t)(qrow0 + nt * 16 + lr) * DD + s * 32 + g * 8;
      qraw[nt][s][0] = *(const f32x4*)qp;
      qraw[nt][s][1] = *(const f32x4*)(qp + 4);
    }

  const int dg = (t & 7) * 8;   // 8 consecutive d per thread
  const int rowt = t >> 3;      // 32 rows per iter

  // ---- stage V (all 256 keys), bf16 via cvt_pk, swizzled ----
#pragma unroll
  for (int it = 0; it < 8; ++it) {
    int key = it * 32 + rowt;
    int j = j0 + key;
    j = j < 0 ? 0 : j;          // clamp; invalid keys never read back
    const float* src = Vb + (size_t)j * DD + dg;
    f32x4 a = *(const f32x4*)src;
    f32x4 c = *(const f32x4*)(src + 4);
    union { u16x8 v; unsigned w[4]; } hv;
    hv.w[0] = cvt_pk_bf16(a[0], a[1]);
    hv.w[1] = cvt_pk_bf16(a[2], a[3]);
    hv.w[2] = cvt_pk_bf16(c[0], c[1]);
    hv.w[3] = cvt_pk_bf16(c[2], c[3]);
    *(u16x8*)(vvs + vswz(key, dg)) = hv.v;
  }

  // ---- Q fragments: plain bf16 of q * (log2e/8) ----
  bf16x8 qb[2][2];
#pragma unroll
  for (int nt = 0; nt < 2; ++nt)
#pragma unroll
    for (int s = 0; s < 2; ++s) {
      union { unsigned w[4]; bf16x8 v; } H;
#pragma unroll
      for (int half = 0; half < 2; ++half)
#pragma unroll
        for (int p = 0; p < 2; ++p)
          H.w[half * 2 + p] = cvt_pk_bf16(qraw[nt][s][half][2 * p] * QSCALE,
                                          qraw[nt][s][half][2 * p + 1] * QSCALE);
      qb[nt][s] = H.v;
    }

  __syncthreads();   // V ready (the only barrier)

  // ---- flash over 4 passes of 64 keys ----
  float m0 = -1e38f, m1 = -1e38f;   // running row max (log2 domain)
  float l0 = 0.f, l1 = 0.f;         // per-lane partial denominators
  f32x4 oacc[2][4];
#pragma unroll
  for (int nt = 0; nt < 2; ++nt)
#pragma unroll
    for (int dt = 0; dt < 4; ++dt)
      oacc[nt][dt] = (f32x4){0.f, 0.f, 0.f, 0.f};

  const int p0 = (i == 0) ? 2 : 0;   // i==0: first 128 window keys invalid
#pragma unroll 1
  for (int p = 0; p < 4; ++p) {
    if (p < p0) continue;
    const int kb0 = p * 64;

    // S^T = K * Q^T for this 64-key tile; K direct from global (L2-hot).
    f32x4 sacc[4][2];
#pragma unroll
    for (int kt = 0; kt < 4; ++kt)
#pragma unroll
      for (int nt = 0; nt < 2; ++nt)
        sacc[kt][nt] = (f32x4){0.f, 0.f, 0.f, 0.f};

#pragma unroll
    for (int kt = 0; kt < 4; ++kt) {
      const float* kp = Kb + (size_t)(j0 + kb0 + kt * 16 + lr) * DD;
#pragma unroll
      for (int s = 0; s < 2; ++s) {
        f32x4 a = *(const f32x4*)(kp + s * 32 + g * 8);
        f32x4 c = *(const f32x4*)(kp + s * 32 + g * 8 + 4);
        union { unsigned w[4]; bf16x8 v; } kf;
        kf.w[0] = cvt_pk_bf16(a[0], a[1]);
        kf.w[1] = cvt_pk_bf16(a[2], a[3]);
        kf.w[2] = cvt_pk_bf16(c[0], c[1]);
        kf.w[3] = cvt_pk_bf16(c[2], c[3]);
        sacc[kt][0] = __builtin_amdgcn_mfma_f32_16x16x32_bf16(kf.v, qb[0][s],
                                                              sacc[kt][0], 0, 0, 0);
        sacc[kt][1] = __builtin_amdgcn_mfma_f32_16x16x32_bf16(kf.v, qb[1][s],
                                                              sacc[kt][1], 0, 0, 0);
      }
    }

    // mask bias + tile max.  C-layout: key = kb0 + kt*16 + 4g + r, qrow = nt*16+lr
    float pm0 = -1e38f, pm1 = -1e38f;
#pragma unroll
    for (int kt = 0; kt < 4; ++kt) {
      f32x4 mv = *(const f32x4*)(Mb + (j0 + kb0 + kt * 16 + 4 * g));
#pragma unroll
      for (int r = 0; r < 4; ++r) {
        float bvr = mv[r] * LOG2E;
        sacc[kt][0][r] += bvr;
        sacc[kt][1][r] += bvr;
      }
      pm0 = max3f(sacc[kt][0][0], sacc[kt][0][1], pm0);
      pm0 = max3f(sacc[kt][0][2], sacc[kt][0][3], pm0);
      pm1 = max3f(sacc[kt][1][0], sacc[kt][1][1], pm1);
      pm1 = max3f(sacc[kt][1][2], sacc[kt][1][3], pm1);
    }
    pm0 = fmaxf(pm0, __shfl_xor(pm0, 16));
    pm0 = fmaxf(pm0, __shfl_xor(pm0, 32));
    pm1 = fmaxf(pm1, __shfl_xor(pm1, 16));
    pm1 = fmaxf(pm1, __shfl_xor(pm1, 32));

    // online update with defer-rescale (P bounded by 2^THR)
    if (!__all(pm0 - m0 <= THR)) {
      float mn = fmaxf(m0, pm0);
      float sc = exp2_hw(m0 - mn);
      l0 *= sc;
#pragma unroll
      for (int dt = 0; dt < 4; ++dt) oacc[0][dt] *= sc;
      m0 = mn;
    }
    if (!__all(pm1 - m1 <= THR)) {
      float mn = fmaxf(m1, pm1);
      float sc = exp2_hw(m1 - mn);
      l1 *= sc;
#pragma unroll
      for (int dt = 0; dt < 4; ++dt) oacc[1][dt] *= sc;
      m1 = mn;
    }

    // P = exp2(S - m); accumulate per-lane partial denominators
#pragma unroll
    for (int kt = 0; kt < 4; ++kt)
#pragma unroll
      for (int r = 0; r < 4; ++r) {
        float q0 = exp2_hw(sacc[kt][0][r] - m0);
        float q1 = exp2_hw(sacc[kt][1][r] - m1);
        sacc[kt][0][r] = q0;
        sacc[kt][1][r] = q1;
        l0 += q0;
        l1 += q1;
      }

    // PV for this tile: A = P (regs), B = V from LDS with matching
    // per-slot key permutation sigma = kb0 + 32c + 16*(jj>>2) + 4g + (jj&3)
#pragma unroll
    for (int c = 0; c < 2; ++c) {
      union { unsigned w[4]; bf16x8 v; } pa[2];
#pragma unroll
      for (int nt = 0; nt < 2; ++nt) {
        pa[nt].w[0] = cvt_pk_bf16(sacc[2 * c][nt][0], sacc[2 * c][nt][1]);
        pa[nt].w[1] = cvt_pk_bf16(sacc[2 * c][nt][2], sacc[2 * c][nt][3]);
        pa[nt].w[2] = cvt_pk_bf16(sacc[2 * c + 1][nt][0], sacc[2 * c + 1][nt][1]);
        pa[nt].w[3] = cvt_pk_bf16(sacc[2 * c + 1][nt][2], sacc[2 * c + 1][nt][3]);
      }
#pragma unroll
      for (int dt = 0; dt < 4; ++dt) {
        union { unsigned short u[8]; bf16x8 v; } vb;
        int d = dt * 16 + lr;
#pragma unroll
        for (int jj = 0; jj < 8; ++jj) {
          int key = kb0 + 32 * c + 16 * (jj >> 2) + 4 * g + (jj & 3);
          vb.u[jj] = vvs[vswz(key, d)];
        }
        oacc[0][dt] = __builtin_amdgcn_mfma_f32_16x16x32_bf16(pa[0].v, vb.v,
                                                              oacc[0][dt], 0, 0, 0);
        oacc[1][dt] = __builtin_amdgcn_mfma_f32_16x16x32_bf16(pa[1].v, vb.v,
                                                              oacc[1][dt], 0, 0, 0);
      }
    }
  }

  // ---- final denominator reduce + epilogue ----
  l0 += __shfl_xor(l0, 16);
  l0 += __shfl_xor(l0, 32);
  l1 += __shfl_xor(l1, 16);
  l1 += __shfl_xor(l1, 32);
  const float inv0 = 1.f / l0;
  const float inv1 = 1.f / l1;

  // out C layout -> row = nt*16 + 4g + r, col = dt*16 + lr
  float* Ob = Og + base + (size_t)qrow0 * DD;
#pragma unroll
  for (int nt = 0; nt < 2; ++nt) {
#pragma unroll
    for (int r = 0; r < 4; ++r) {
      float iv = __shfl(nt ? inv1 : inv0, 4 * g + r);
      int row = nt * 16 + 4 * g + r;
#pragma unroll
      for (int dt = 0; dt < 4; ++dt)
        Ob[(size_t)row * DD + dt * 16 + lr] = oacc[nt][dt][r] * iv;
    }
  }
}

extern "C" void kernel_launch(void* const* d_in, const int* in_sizes, int n_in,
                              void* d_out, int out_size, void* d_ws, size_t ws_size,
                              hipStream_t stream) {
  (void)in_sizes; (void)n_in; (void)out_size; (void)d_ws; (void)ws_size;
  const float* Q = (const float*)d_in[0];
  const float* K = (const float*)d_in[1];
  const float* V = (const float*)d_in[2];
  const float* M = (const float*)d_in[3];
  float* O = (float*)d_out;

  hipLaunchKernelGGL(swa_fwd, dim3(NB * NH * 32), dim3(256), 0, stream,
                     Q, K, V, M, O);
}